// Round 4
// baseline (162.852 us; speedup 1.0000x reference)
//
#include <hip/hip_runtime.h>
#include <hip/hip_bf16.h>
#include <cstddef>

#define NHEADS 9
#define D 32
#define SQ 4096
#define ZSPLIT 8
#define MBLK (SQ / ZSPLIT)     // 512 m per block
#define NSTEPS (MBLK / 32)     // 16 compute steps of 32 m

typedef __attribute__((ext_vector_type(8))) short bf16x8;
typedef __attribute__((ext_vector_type(4))) float f32x4;

__device__ __forceinline__ unsigned int f2bf(float f) {
    unsigned int u = __float_as_uint(f);
    u += 0x7fffu + ((u >> 16) & 1u);
    return u >> 16;
}

// pack two f32 into bf16x2 by TRUNCATION: one v_perm_b32.
__device__ __forceinline__ unsigned int trunc_pk(float lo, float hi) {
    return __builtin_amdgcn_perm(__float_as_uint(hi), __float_as_uint(lo),
                                 0x07060302u);
}

// Pack 8 scores (two QK C-tiles) then relu on bf16 BIT PATTERNS:
// negative bf16 == negative i16, so relu == v_pk_max_i16(p, 0).
__device__ __forceinline__ bf16x8 relu_pack8(f32x4 s1, f32x4 s2) {
    union { unsigned int u[4]; bf16x8 v; } P;
    P.u[0] = trunc_pk(s1[0], s1[1]);
    P.u[1] = trunc_pk(s1[2], s1[3]);
    P.u[2] = trunc_pk(s2[0], s2[1]);
    P.u[3] = trunc_pk(s2[2], s2[3]);
    const bf16x8 z = {0, 0, 0, 0, 0, 0, 0, 0};
    return __builtin_elementwise_max(P.v, z);   // v_pk_max_i16 x4
}

// ---------------------------------------------------------------------------
// Prep: bilinear upsample (32->64, half-pixel) + 1x1 convs -> Q,K,V (bf16) + t
// One thread per (bh, n, 8-d-group).
// K is written in CHUNK-SLOT-PERMUTED layout: [bh][chunk=n>>6][slot(n&63)][d],
// slot = bit-shuffle (b5,b4,b3,b2,b1,b0)->(b5,b2,b4,b3,b1,b0) — the exact
// permutation the old LDS staging applied, so attn waves can read MFMA
// A-fragments DIRECTLY from global as contiguous coalesced 1KB wave-loads.
// V transposed to [bh][d][m] THROUGH LDS (stride-66 scatter = conflict-free).
// ---------------------------------------------------------------------------
__global__ __launch_bounds__(256) void prep_kernel(
    const float* __restrict__ x2, const float* __restrict__ x1,
    const float* __restrict__ feat1,
    const float* __restrict__ Wq, const float* __restrict__ bq,
    const float* __restrict__ Wk, const float* __restrict__ bk,
    const float* __restrict__ Wv, const float* __restrict__ bv,
    const float* __restrict__ Wt, const float* __restrict__ bt,
    unsigned short* __restrict__ Qb, unsigned short* __restrict__ Kb,
    unsigned short* __restrict__ Vt, float* __restrict__ tbuf)
{
    __shared__ unsigned short Vls[32 * 66];   // [d][n_local], stride 66

    const int tid = threadIdx.x;
    int idx = blockIdx.x * blockDim.x + tid;   // 0 .. 2*9*4096*4-1
    int g  = idx & 3;                 // d-group: d = g*8 .. g*8+7
    int nl = tid >> 2;                // n-local 0..63 (block covers 64 n, 1 bh)
    int n  = (idx >> 2) & (SQ - 1);
    int bh = idx >> 14;               // 0..17
    int h  = bh % NHEADS;
    int b  = bh / NHEADS;

    float xs0 = x2[((size_t)b * 3 + 0) * SQ + n];
    float xs1 = x2[((size_t)b * 3 + 1) * SQ + n];
    float xs2 = x2[((size_t)b * 3 + 2) * SQ + n];
    float ys0 = x1[((size_t)b * 3 + 0) * SQ + n];
    float ys1 = x1[((size_t)b * 3 + 1) * SQ + n];
    float ys2 = x1[((size_t)b * 3 + 2) * SQ + n];

    // bilinear upsample coords: src = i*0.5 - 0.25 (half-pixel)
    int yy = n >> 6, xx = n & 63;
    int jy = yy >> 1, jx = xx >> 1;
    int j0, j1, i0, i1; float wy0, wy1, wx0, wx1;
    if (yy & 1) { j0 = jy; j1 = (jy < 31) ? jy + 1 : 31; wy0 = 0.75f; wy1 = 0.25f; }
    else        { j0 = (jy > 0) ? jy - 1 : 0; j1 = jy;   wy0 = 0.25f; wy1 = 0.75f; }
    if (xx & 1) { i0 = jx; i1 = (jx < 31) ? jx + 1 : 31; wx0 = 0.75f; wx1 = 0.25f; }
    else        { i0 = (jx > 0) ? jx - 1 : 0; i1 = jx;   wx0 = 0.25f; wx1 = 0.75f; }

    float fu[4];
#pragma unroll
    for (int c = 0; c < 4; ++c) {
        const float* f = feat1 + ((size_t)b * 4 + c) * 1024;
        fu[c] = wy0 * (wx0 * f[j0 * 32 + i0] + wx1 * f[j0 * 32 + i1]) +
                wy1 * (wx0 * f[j1 * 32 + i0] + wx1 * f[j1 * 32 + i1]);
    }

    const int d0 = g * 8;
    unsigned int qp[4], kp[4];
    float tpart = 0.0f;
#pragma unroll
    for (int j = 0; j < 8; ++j) {
        int d = d0 + j, hd = h * D + d;
        float q = bq[hd] + Wq[hd * 3] * xs0 + Wq[hd * 3 + 1] * xs1 + Wq[hd * 3 + 2] * xs2;
        float k = bk[hd] + Wk[hd * 3] * ys0 + Wk[hd * 3 + 1] * ys1 + Wk[hd * 3 + 2] * ys2;
        float v = bv[hd] + Wv[hd * 4] * fu[0] + Wv[hd * 4 + 1] * fu[1] +
                  Wv[hd * 4 + 2] * fu[2] + Wv[hd * 4 + 3] * fu[3];
        tpart += q * Wt[d];
        unsigned int qb_ = f2bf(q), kb_ = f2bf(k);
        if (j & 1) { qp[j >> 1] |= qb_ << 16; kp[j >> 1] |= kb_ << 16; }
        else       { qp[j >> 1]  = qb_;       kp[j >> 1]  = kb_; }
        Vls[d * 66 + nl] = (unsigned short)f2bf(v);   // conflict-free scatter
    }
    // reduce threshold partial over the 4-lane d-group
    tpart += __shfl_xor(tpart, 1);
    tpart += __shfl_xor(tpart, 2);
    if (g == 0) tbuf[(size_t)bh * SQ + n] = tpart + bt[0];

    *(uint4*)(Qb + ((size_t)bh * SQ + n) * D + d0) =
        make_uint4(qp[0], qp[1], qp[2], qp[3]);

    // K: permuted-slot write (bijective within each 64-row chunk)
    {
        int nl_  = n & 63;
        int slot = (nl_ & 32) + 4 * ((nl_ >> 3) & 3) + (nl_ & 3) + ((nl_ & 4) << 2);
        size_t kaddr = ((size_t)bh * SQ + (n & ~63) + slot) * D + d0;
        *(uint4*)(Kb + kaddr) = make_uint4(kp[0], kp[1], kp[2], kp[3]);
    }

    __syncthreads();
    // coalesced V write-out: thread -> row r = tid>>3, 4-u16 chunk c4 = tid&7
    {
        int r  = tid >> 3;
        int c4 = tid & 7;
        int n0 = (blockIdx.x & 63) * 64;
        unsigned int w0 = *(const unsigned int*)&Vls[r * 66 + c4 * 4];
        unsigned int w1 = *(const unsigned int*)&Vls[r * 66 + c4 * 4 + 2];
        *(uint2*)(Vt + ((size_t)bh * D + r) * SQ + n0 + c4 * 4) = make_uint2(w0, w1);
    }
}

// ---------------------------------------------------------------------------
// Attention: NO LDS, NO BARRIERS. Each wave is an independent stream:
// per 32-m step, 4 coalesced 16B global loads (K fragments contiguous 1KB/
// wave thanks to prep's permuted layout; V = 16 rows x 64B) -> 8 QK MFMA
// (threshold folded into C) -> relu+trunc pack -> 8 PV MFMA. A/B register
// double-buffer covers L2 latency; 4 waves/SIMD (VGPR<=128, LDS=0) provide
// TLP. K+V per bh = 512KB, L2-resident per XCD via the round-1 decode, so
// LDS sharing bought nothing (common-mistake #7) while costing per-chunk
// lgkm barriers + convoy + 2.95M bank-conflict cycles.
// Epilogue: plain stores of per-(bh,zz) partials (round-2 post-mortem:
// atomicAdd bypasses L2 write-combining; never use it on hot paths).
// ---------------------------------------------------------------------------
#define STEP_LOAD(S, K1, K2, VL, VH)                                           \
    K1 = *(const bf16x8*)(kbase + (size_t)(S) * (32 * D));                     \
    K2 = *(const bf16x8*)(kbase + (size_t)(S) * (32 * D) + 16 * D);            \
    VL = *(const bf16x8*)(vbase + (S) * 32);                                   \
    VH = *(const bf16x8*)(vbase + (S) * 32 + 16 * SQ);

#define STEP_COMPUTE(K1, K2, VL, VH)                                           \
    {                                                                          \
        f32x4 sA1 = __builtin_amdgcn_mfma_f32_16x16x32_bf16(K1, qfA, ciA, 0, 0, 0);\
        f32x4 sA2 = __builtin_amdgcn_mfma_f32_16x16x32_bf16(K2, qfA, ciA, 0, 0, 0);\
        f32x4 sB1 = __builtin_amdgcn_mfma_f32_16x16x32_bf16(K1, qfB, ciB, 0, 0, 0);\
        f32x4 sB2 = __builtin_amdgcn_mfma_f32_16x16x32_bf16(K2, qfB, ciB, 0, 0, 0);\
        f32x4 sC1 = __builtin_amdgcn_mfma_f32_16x16x32_bf16(K1, qfC, ciC, 0, 0, 0);\
        f32x4 sC2 = __builtin_amdgcn_mfma_f32_16x16x32_bf16(K2, qfC, ciC, 0, 0, 0);\
        f32x4 sD1 = __builtin_amdgcn_mfma_f32_16x16x32_bf16(K1, qfD, ciD, 0, 0, 0);\
        f32x4 sD2 = __builtin_amdgcn_mfma_f32_16x16x32_bf16(K2, qfD, ciD, 0, 0, 0);\
        bf16x8 pA = relu_pack8(sA1, sA2);                                      \
        bf16x8 pB = relu_pack8(sB1, sB2);                                      \
        bf16x8 pC = relu_pack8(sC1, sC2);                                      \
        bf16x8 pD = relu_pack8(sD1, sD2);                                      \
        accAl = __builtin_amdgcn_mfma_f32_16x16x32_bf16(VL, pA, accAl, 0, 0, 0);\
        accAh = __builtin_amdgcn_mfma_f32_16x16x32_bf16(VH, pA, accAh, 0, 0, 0);\
        accBl = __builtin_amdgcn_mfma_f32_16x16x32_bf16(VL, pB, accBl, 0, 0, 0);\
        accBh = __builtin_amdgcn_mfma_f32_16x16x32_bf16(VH, pB, accBh, 0, 0, 0);\
        accCl = __builtin_amdgcn_mfma_f32_16x16x32_bf16(VL, pC, accCl, 0, 0, 0);\
        accCh = __builtin_amdgcn_mfma_f32_16x16x32_bf16(VH, pC, accCh, 0, 0, 0);\
        accDl = __builtin_amdgcn_mfma_f32_16x16x32_bf16(VL, pD, accDl, 0, 0, 0);\
        accDh = __builtin_amdgcn_mfma_f32_16x16x32_bf16(VH, pD, accDh, 0, 0, 0);\
    }

__global__ __launch_bounds__(256, 4) void attn_kernel(
    const unsigned short* __restrict__ Qb,
    const unsigned short* __restrict__ Kb,
    const unsigned short* __restrict__ Vt,
    const float* __restrict__ tbuf,
    const float* __restrict__ Wp,
    float* __restrict__ ofp)
{
    // XCD-aware bijective decode: lin -> (xcd 0..7, q 0..287) ->
    // (group-local 0..17, xblk 0..15); group = xcd*18+gl -> (bh, z).
    const int lin  = blockIdx.x;
    const int xcd  = lin & 7;
    const int q8   = lin >> 3;           // 0..287
    const int xblk = q8 & 15;
    const int gl   = q8 >> 4;            // 0..17
    const int grp  = xcd * 18 + gl;      // 0..143
    const int bh   = grp >> 3;           // 0..17
    const int zz   = grp & 7;            // 0..7
    const int h    = bh % NHEADS;
    const int n0   = xblk * 256;
    const int mc0  = zz * MBLK;
    const int tid  = threadIdx.x;
    const int wave = tid >> 6;
    const int lane = tid & 63;
    const int l15  = lane & 15;
    const int quad = lane >> 4;

    const int nw = n0 + wave * 64;

    // Q as B-fragment: B[d=quad*8+j][n=l15], 4 tiles at n offsets 0/16/32/48
    const unsigned short* qbase = Qb + ((size_t)bh * SQ + nw + l15) * D + quad * 8;
    bf16x8 qfA = *(const bf16x8*)(qbase);
    bf16x8 qfB = *(const bf16x8*)(qbase + 16 * D);
    bf16x8 qfC = *(const bf16x8*)(qbase + 32 * D);
    bf16x8 qfD = *(const bf16x8*)(qbase + 48 * D);

    const float SQRT32 = 5.656854249492381f;
    const float* tb = tbuf + (size_t)bh * SQ + nw + l15;
    float TA = tb[0]  * SQRT32;
    float TB = tb[16] * SQRT32;
    float TC = tb[32] * SQRT32;
    float TD = tb[48] * SQRT32;
    const f32x4 ciA = {-TA, -TA, -TA, -TA};
    const f32x4 ciB = {-TB, -TB, -TB, -TB};
    const f32x4 ciC = {-TC, -TC, -TC, -TC};
    const f32x4 ciD = {-TD, -TD, -TD, -TD};

    // direct-global fragment bases (K folds mc0 + l15 row; V folds d-row l15)
    const unsigned short* kbase = Kb + ((size_t)bh * SQ + mc0 + l15) * D + quad * 8;
    const unsigned short* vbase = Vt + ((size_t)bh * D + l15) * SQ + mc0 + quad * 8;

    f32x4 accAl = {0.f,0.f,0.f,0.f}, accAh = {0.f,0.f,0.f,0.f};
    f32x4 accBl = {0.f,0.f,0.f,0.f}, accBh = {0.f,0.f,0.f,0.f};
    f32x4 accCl = {0.f,0.f,0.f,0.f}, accCh = {0.f,0.f,0.f,0.f};
    f32x4 accDl = {0.f,0.f,0.f,0.f}, accDh = {0.f,0.f,0.f,0.f};

    // A/B register double-buffer: while computing one step's fragments the
    // other set's loads are in flight (cover ~= one STEP_COMPUTE >= L2 lat).
    bf16x8 k1a, k2a, vla, vha, k1b, k2b, vlb, vhb;
    STEP_LOAD(0, k1a, k2a, vla, vha);
#pragma unroll
    for (int s = 0; s < NSTEPS; s += 2) {
        STEP_LOAD(s + 1, k1b, k2b, vlb, vhb);
        STEP_COMPUTE(k1a, k2a, vla, vha);
        {
            const int na = (s + 2 < NSTEPS) ? s + 2 : NSTEPS - 1;  // tail: dead
            STEP_LOAD(na, k1a, k2a, vla, vha);
        }
        STEP_COMPUTE(k1b, k2b, vlb, vhb);
    }

    // lane holds out^T[d = quad*4+r (lo) / 16+... (hi)][n] (x sqrt(32)*3000).
    // Project 288->4 with Wp, apply deferred scale, reduce quads, and STORE
    // the per-(bh,zz) partial into this block's unique of_part region.
    const float s1 = 5.892556509887896e-05f;   // 1/(sqrt(32)*3000)
    const float* wph = Wp + h * D + quad * 4;
    float* obase = ofp + ((size_t)(bh * 8 + zz) * 4) * SQ + nw + l15;
#pragma unroll
    for (int o = 0; o < 4; ++o) {
        float cA = 0.f, cB = 0.f, cC = 0.f, cD = 0.f;
#pragma unroll
        for (int r = 0; r < 4; ++r) {
            float wlo = wph[o * 288 + r], whi = wph[o * 288 + 16 + r];
            cA += accAl[r] * wlo + accAh[r] * whi;
            cB += accBl[r] * wlo + accBh[r] * whi;
            cC += accCl[r] * wlo + accCh[r] * whi;
            cD += accDl[r] * wlo + accDh[r] * whi;
        }
        cA += __shfl_xor(cA, 16); cA += __shfl_xor(cA, 32);
        cB += __shfl_xor(cB, 16); cB += __shfl_xor(cB, 32);
        cC += __shfl_xor(cC, 16); cC += __shfl_xor(cC, 32);
        cD += __shfl_xor(cD, 16); cD += __shfl_xor(cD, 32);
        if (quad == 0) {
            float* ob = obase + (size_t)o * SQ;
            ob[0]  = cA * s1;
            ob[16] = cB * s1;
            ob[32] = cC * s1;
            ob[48] = cD * s1;
        }
    }
}

// ---------------------------------------------------------------------------
// Final: 72-way partial reduction (9 h x 8 zz) fused with 2x2-mean
// downsample + bias + residual; both tuple outputs.
// 65536 threads: 8 per output (one zz-slice each, 9-h loop), shfl reduce.
// ---------------------------------------------------------------------------
__global__ __launch_bounds__(256) void final_kernel(
    const float* __restrict__ ofp,
    const float* __restrict__ sff,
    const float* __restrict__ bp,
    float* __restrict__ dout)
{
    int t = blockIdx.x * 256 + threadIdx.x;   // 0..65535
    int out = t >> 3;                         // 0..8191 output index
    int s   = t & 7;                          // zz slice
    int i  = out & 31;
    int jj = (out >> 5) & 31;
    int bo = out >> 10;
    int o  = bo & 3;
    int b  = bo >> 2;
    int nbase = (jj * 2) * 64 + i * 2;

    float acc = 0.0f;
#pragma unroll
    for (int h = 0; h < NHEADS; ++h) {
        const float* src = ofp +
            ((size_t)(((b * NHEADS + h) * 8 + s) * 4 + o)) * SQ + nbase;
        acc += src[0] + src[1] + src[64] + src[65];
    }
    acc += __shfl_xor(acc, 1);
    acc += __shfl_xor(acc, 2);
    acc += __shfl_xor(acc, 4);
    if (s == 0) {
        float dval = 0.25f * acc + bp[o];
        dout[out]        = sff[out] + dval;
        dout[8192 + out] = dval;
    }
}

extern "C" void kernel_launch(void* const* d_in, const int* in_sizes, int n_in,
                              void* d_out, int out_size, void* d_ws, size_t ws_size,
                              hipStream_t stream)
{
    const float* second_frame = (const float*)d_in[0];
    const float* first_frame  = (const float*)d_in[1];
    const float* sff          = (const float*)d_in[2];
    const float* ffa          = (const float*)d_in[3];
    const float* Wq = (const float*)d_in[4];
    const float* bq = (const float*)d_in[5];
    const float* Wk = (const float*)d_in[6];
    const float* bk = (const float*)d_in[7];
    const float* Wv = (const float*)d_in[8];
    const float* bv = (const float*)d_in[9];
    const float* Wp = (const float*)d_in[10];
    const float* bp = (const float*)d_in[11];
    const float* Wt = (const float*)d_in[12];
    const float* bt = (const float*)d_in[13];
    float* out = (float*)d_out;

    char* ws = (char*)d_ws;
    const size_t QKV = (size_t)2 * NHEADS * SQ * D * sizeof(unsigned short);
    unsigned short* Qb = (unsigned short*)ws;
    unsigned short* Kb = (unsigned short*)(ws + QKV);
    unsigned short* Vt = (unsigned short*)(ws + 2 * QKV);
    float* tbuf = (float*)(ws + 3 * QKV);
    // of_part[18 bh][8 zz][4 o][4096 n] = 9.44 MB of partials
    float* ofp  = (float*)(ws + 3 * QKV + (size_t)2 * NHEADS * SQ * sizeof(float));

    prep_kernel<<<1152, 256, 0, stream>>>(second_frame, first_frame, ffa,
                                          Wq, bq, Wk, bk, Wv, bv, Wt, bt,
                                          Qb, Kb, Vt, tbuf);
    attn_kernel<<<16 * 18 * ZSPLIT, 256, 0, stream>>>(Qb, Kb, Vt, tbuf, Wp, ofp);
    final_kernel<<<256, 256, 0, stream>>>(ofp, sff, bp, out);
}

// Round 5
// 142.266 us; speedup vs baseline: 1.1447x; 1.1447x over previous
//
#include <hip/hip_runtime.h>
#include <hip/hip_bf16.h>
#include <cstddef>

#define NHEADS 9
#define D 32
#define SQ 4096
#define ZSPLIT 8
#define MBLK (SQ / ZSPLIT)     // 512 m per block
#define NSTEPS (MBLK / 32)     // 16 compute steps of 32 m

typedef __attribute__((ext_vector_type(8))) short bf16x8;
typedef __attribute__((ext_vector_type(4))) float f32x4;

__device__ __forceinline__ unsigned int f2bf(float f) {
    unsigned int u = __float_as_uint(f);
    u += 0x7fffu + ((u >> 16) & 1u);
    return u >> 16;
}

// pack two f32 into bf16x2 by TRUNCATION: one v_perm_b32.
__device__ __forceinline__ unsigned int trunc_pk(float lo, float hi) {
    return __builtin_amdgcn_perm(__float_as_uint(hi), __float_as_uint(lo),
                                 0x07060302u);
}

// Pack 8 scores (two QK C-tiles) then relu on bf16 BIT PATTERNS:
// negative bf16 == negative i16, so relu == v_pk_max_i16(p, 0).
__device__ __forceinline__ bf16x8 relu_pack8(f32x4 s1, f32x4 s2) {
    union { unsigned int u[4]; bf16x8 v; } P;
    P.u[0] = trunc_pk(s1[0], s1[1]);
    P.u[1] = trunc_pk(s1[2], s1[3]);
    P.u[2] = trunc_pk(s2[0], s2[1]);
    P.u[3] = trunc_pk(s2[2], s2[3]);
    const bf16x8 z = {0, 0, 0, 0, 0, 0, 0, 0};
    return __builtin_elementwise_max(P.v, z);   // v_pk_max_i16 x4
}

// ---------------------------------------------------------------------------
// Prep: bilinear upsample (32->64, half-pixel) + 1x1 convs -> Q,K,V (bf16) + t
// One thread per (bh, n, 8-d-group).
// K: CHUNK-SLOT-PERMUTED layout [bh][chunk=n>>6][slot(n&63)][d] (the old LDS
// staging permutation) so attn K-fragments are contiguous 1KB wave-loads.
// V: FRAGMENT-ORDERED layout — per 32-m chunk a 2KB block
//   addr = (bh*128 + m>>5)*1024 + (d>>4)*512 + ((m>>3)&3)*128 + (d&15)*8 + (m&7)
// so attn VL/VH fragments are each ONE contiguous 1KB wave-load (round-4
// post-mortem: the old [d][m] layout made every V load a 16-segment scatter
// at 8KB stride = L2 latency x16 requests). Transpose goes through LDS
// (stride-66 scatter = conflict-free); write-out is one uint4 per thread
// (full 64-n coverage).
// ---------------------------------------------------------------------------
__global__ __launch_bounds__(256) void prep_kernel(
    const float* __restrict__ x2, const float* __restrict__ x1,
    const float* __restrict__ feat1,
    const float* __restrict__ Wq, const float* __restrict__ bq,
    const float* __restrict__ Wk, const float* __restrict__ bk,
    const float* __restrict__ Wv, const float* __restrict__ bv,
    const float* __restrict__ Wt, const float* __restrict__ bt,
    unsigned short* __restrict__ Qb, unsigned short* __restrict__ Kb,
    unsigned short* __restrict__ Vt, float* __restrict__ tbuf)
{
    __shared__ unsigned short Vls[32 * 66];   // [d][n_local], stride 66

    const int tid = threadIdx.x;
    int idx = blockIdx.x * blockDim.x + tid;   // 0 .. 2*9*4096*4-1
    int g  = idx & 3;                 // d-group: d = g*8 .. g*8+7
    int nl = tid >> 2;                // n-local 0..63 (block covers 64 n, 1 bh)
    int n  = (idx >> 2) & (SQ - 1);
    int bh = idx >> 14;               // 0..17
    int h  = bh % NHEADS;
    int b  = bh / NHEADS;

    float xs0 = x2[((size_t)b * 3 + 0) * SQ + n];
    float xs1 = x2[((size_t)b * 3 + 1) * SQ + n];
    float xs2 = x2[((size_t)b * 3 + 2) * SQ + n];
    float ys0 = x1[((size_t)b * 3 + 0) * SQ + n];
    float ys1 = x1[((size_t)b * 3 + 1) * SQ + n];
    float ys2 = x1[((size_t)b * 3 + 2) * SQ + n];

    // bilinear upsample coords: src = i*0.5 - 0.25 (half-pixel)
    int yy = n >> 6, xx = n & 63;
    int jy = yy >> 1, jx = xx >> 1;
    int j0, j1, i0, i1; float wy0, wy1, wx0, wx1;
    if (yy & 1) { j0 = jy; j1 = (jy < 31) ? jy + 1 : 31; wy0 = 0.75f; wy1 = 0.25f; }
    else        { j0 = (jy > 0) ? jy - 1 : 0; j1 = jy;   wy0 = 0.25f; wy1 = 0.75f; }
    if (xx & 1) { i0 = jx; i1 = (jx < 31) ? jx + 1 : 31; wx0 = 0.75f; wx1 = 0.25f; }
    else        { i0 = (jx > 0) ? jx - 1 : 0; i1 = jx;   wx0 = 0.25f; wx1 = 0.75f; }

    float fu[4];
#pragma unroll
    for (int c = 0; c < 4; ++c) {
        const float* f = feat1 + ((size_t)b * 4 + c) * 1024;
        fu[c] = wy0 * (wx0 * f[j0 * 32 + i0] + wx1 * f[j0 * 32 + i1]) +
                wy1 * (wx0 * f[j1 * 32 + i0] + wx1 * f[j1 * 32 + i1]);
    }

    const int d0 = g * 8;
    unsigned int qp[4], kp[4];
    float tpart = 0.0f;
#pragma unroll
    for (int j = 0; j < 8; ++j) {
        int d = d0 + j, hd = h * D + d;
        float q = bq[hd] + Wq[hd * 3] * xs0 + Wq[hd * 3 + 1] * xs1 + Wq[hd * 3 + 2] * xs2;
        float k = bk[hd] + Wk[hd * 3] * ys0 + Wk[hd * 3 + 1] * ys1 + Wk[hd * 3 + 2] * ys2;
        float v = bv[hd] + Wv[hd * 4] * fu[0] + Wv[hd * 4 + 1] * fu[1] +
                  Wv[hd * 4 + 2] * fu[2] + Wv[hd * 4 + 3] * fu[3];
        tpart += q * Wt[d];
        unsigned int qb_ = f2bf(q), kb_ = f2bf(k);
        if (j & 1) { qp[j >> 1] |= qb_ << 16; kp[j >> 1] |= kb_ << 16; }
        else       { qp[j >> 1]  = qb_;       kp[j >> 1]  = kb_; }
        Vls[d * 66 + nl] = (unsigned short)f2bf(v);   // conflict-free scatter
    }
    // reduce threshold partial over the 4-lane d-group
    tpart += __shfl_xor(tpart, 1);
    tpart += __shfl_xor(tpart, 2);
    if (g == 0) tbuf[(size_t)bh * SQ + n] = tpart + bt[0];

    *(uint4*)(Qb + ((size_t)bh * SQ + n) * D + d0) =
        make_uint4(qp[0], qp[1], qp[2], qp[3]);

    // K: permuted-slot write (bijective within each 64-row chunk)
    {
        int nl_  = n & 63;
        int slot = (nl_ & 32) + 4 * ((nl_ >> 3) & 3) + (nl_ & 3) + ((nl_ & 4) << 2);
        size_t kaddr = ((size_t)bh * SQ + (n & ~63) + slot) * D + d0;
        *(uint4*)(Kb + kaddr) = make_uint4(kp[0], kp[1], kp[2], kp[3]);
    }

    __syncthreads();
    // V write-out in fragment order: thread -> d-row r = tid>>3, n-octet
    // c4 = tid&7 (8 n each, FULL 64-n coverage, one 16B store).
    {
        int r   = tid >> 3;          // d 0..31
        int c4  = tid & 7;           // n-octet
        int blk = blockIdx.x & 63;   // 64-n range within bh
        unsigned int w0 = *(const unsigned int*)&Vls[r * 66 + c4 * 8];
        unsigned int w1 = *(const unsigned int*)&Vls[r * 66 + c4 * 8 + 2];
        unsigned int w2 = *(const unsigned int*)&Vls[r * 66 + c4 * 8 + 4];
        unsigned int w3 = *(const unsigned int*)&Vls[r * 66 + c4 * 8 + 6];
        size_t dst = ((size_t)bh * 128 + blk * 2 + (c4 >> 2)) * 1024
                   + (r >> 4) * 512 + (c4 & 3) * 128 + (r & 15) * 8;
        *(uint4*)(Vt + dst) = make_uint4(w0, w1, w2, w3);
    }
}

// ---------------------------------------------------------------------------
// Attention: NO LDS, NO BARRIERS. Each wave is an independent stream:
// per 32-m step, 4 contiguous 1KB wave-loads (K1,K2 from the permuted K
// layout; VL,VH from the fragment-ordered V layout) -> 8 QK MFMA (threshold
// folded into C) -> relu+trunc pack -> 8 PV MFMA.
// THREE-set rotating register pipeline: each set is consumed TWO compute
// phases (~300 cyc) after its loads issue — above L2-hit latency (~225).
// 4 waves/block read identical K/V addresses -> L1 serves repeats.
// K+V per bh = 512KB, L2-resident per XCD via the XCD-aware decode.
// Epilogue: plain stores of per-(bh,zz) partials (round-2 post-mortem:
// atomicAdd bypasses L2 write-combining; never use it on hot paths).
// ---------------------------------------------------------------------------
#define STEP_LOAD(S, K1, K2, VL, VH)                                           \
    K1 = *(const bf16x8*)(kbase + (size_t)(S) * (32 * D));                     \
    K2 = *(const bf16x8*)(kbase + (size_t)(S) * (32 * D) + 16 * D);            \
    VL = *(const bf16x8*)(vbase + (size_t)(S) * 1024);                         \
    VH = *(const bf16x8*)(vbase + (size_t)(S) * 1024 + 512);

#define STEP_COMPUTE(K1, K2, VL, VH)                                           \
    {                                                                          \
        f32x4 sA1 = __builtin_amdgcn_mfma_f32_16x16x32_bf16(K1, qfA, ciA, 0, 0, 0);\
        f32x4 sA2 = __builtin_amdgcn_mfma_f32_16x16x32_bf16(K2, qfA, ciA, 0, 0, 0);\
        f32x4 sB1 = __builtin_amdgcn_mfma_f32_16x16x32_bf16(K1, qfB, ciB, 0, 0, 0);\
        f32x4 sB2 = __builtin_amdgcn_mfma_f32_16x16x32_bf16(K2, qfB, ciB, 0, 0, 0);\
        f32x4 sC1 = __builtin_amdgcn_mfma_f32_16x16x32_bf16(K1, qfC, ciC, 0, 0, 0);\
        f32x4 sC2 = __builtin_amdgcn_mfma_f32_16x16x32_bf16(K2, qfC, ciC, 0, 0, 0);\
        f32x4 sD1 = __builtin_amdgcn_mfma_f32_16x16x32_bf16(K1, qfD, ciD, 0, 0, 0);\
        f32x4 sD2 = __builtin_amdgcn_mfma_f32_16x16x32_bf16(K2, qfD, ciD, 0, 0, 0);\
        bf16x8 pA = relu_pack8(sA1, sA2);                                      \
        bf16x8 pB = relu_pack8(sB1, sB2);                                      \
        bf16x8 pC = relu_pack8(sC1, sC2);                                      \
        bf16x8 pD = relu_pack8(sD1, sD2);                                      \
        accAl = __builtin_amdgcn_mfma_f32_16x16x32_bf16(VL, pA, accAl, 0, 0, 0);\
        accAh = __builtin_amdgcn_mfma_f32_16x16x32_bf16(VH, pA, accAh, 0, 0, 0);\
        accBl = __builtin_amdgcn_mfma_f32_16x16x32_bf16(VL, pB, accBl, 0, 0, 0);\
        accBh = __builtin_amdgcn_mfma_f32_16x16x32_bf16(VH, pB, accBh, 0, 0, 0);\
        accCl = __builtin_amdgcn_mfma_f32_16x16x32_bf16(VL, pC, accCl, 0, 0, 0);\
        accCh = __builtin_amdgcn_mfma_f32_16x16x32_bf16(VH, pC, accCh, 0, 0, 0);\
        accDl = __builtin_amdgcn_mfma_f32_16x16x32_bf16(VL, pD, accDl, 0, 0, 0);\
        accDh = __builtin_amdgcn_mfma_f32_16x16x32_bf16(VH, pD, accDh, 0, 0, 0);\
    }

// one pipeline line: load step (for 2 lines ahead) into one set, compute another
#define PIPE(SL, KL1, KL2, VLL, VLH, KC1, KC2, VCL, VCH)                       \
    STEP_LOAD(SL, KL1, KL2, VLL, VLH);                                         \
    STEP_COMPUTE(KC1, KC2, VCL, VCH);

__global__ __launch_bounds__(256, 4) void attn_kernel(
    const unsigned short* __restrict__ Qb,
    const unsigned short* __restrict__ Kb,
    const unsigned short* __restrict__ Vt,
    const float* __restrict__ tbuf,
    const float* __restrict__ Wp,
    float* __restrict__ ofp)
{
    // XCD-aware bijective decode: lin -> (xcd 0..7, q 0..287) ->
    // (group-local 0..17, xblk 0..15); group = xcd*18+gl -> (bh, z).
    const int lin  = blockIdx.x;
    const int xcd  = lin & 7;
    const int q8   = lin >> 3;           // 0..287
    const int xblk = q8 & 15;
    const int gl   = q8 >> 4;            // 0..17
    const int grp  = xcd * 18 + gl;      // 0..143
    const int bh   = grp >> 3;           // 0..17
    const int zz   = grp & 7;            // 0..7
    const int h    = bh % NHEADS;
    const int n0   = xblk * 256;
    const int mc0  = zz * MBLK;
    const int tid  = threadIdx.x;
    const int wave = tid >> 6;
    const int lane = tid & 63;
    const int l15  = lane & 15;
    const int quad = lane >> 4;

    const int nw = n0 + wave * 64;

    // Q as B-fragment: B[d=quad*8+j][n=l15], 4 tiles at n offsets 0/16/32/48
    const unsigned short* qbase = Qb + ((size_t)bh * SQ + nw + l15) * D + quad * 8;
    bf16x8 qfA = *(const bf16x8*)(qbase);
    bf16x8 qfB = *(const bf16x8*)(qbase + 16 * D);
    bf16x8 qfC = *(const bf16x8*)(qbase + 32 * D);
    bf16x8 qfD = *(const bf16x8*)(qbase + 48 * D);

    const float SQRT32 = 5.656854249492381f;
    const float* tb = tbuf + (size_t)bh * SQ + nw + l15;
    float TA = tb[0]  * SQRT32;
    float TB = tb[16] * SQRT32;
    float TC = tb[32] * SQRT32;
    float TD = tb[48] * SQRT32;
    const f32x4 ciA = {-TA, -TA, -TA, -TA};
    const f32x4 ciB = {-TB, -TB, -TB, -TB};
    const f32x4 ciC = {-TC, -TC, -TC, -TC};
    const f32x4 ciD = {-TD, -TD, -TD, -TD};

    // direct-global fragment bases
    const unsigned short* kbase = Kb + ((size_t)bh * SQ + mc0 + l15) * D + quad * 8;
    const unsigned short* vbase = Vt + ((size_t)bh * 128 + (mc0 >> 5)) * 1024 + lane * 8;

    f32x4 accAl = {0.f,0.f,0.f,0.f}, accAh = {0.f,0.f,0.f,0.f};
    f32x4 accBl = {0.f,0.f,0.f,0.f}, accBh = {0.f,0.f,0.f,0.f};
    f32x4 accCl = {0.f,0.f,0.f,0.f}, accCh = {0.f,0.f,0.f,0.f};
    f32x4 accDl = {0.f,0.f,0.f,0.f}, accDh = {0.f,0.f,0.f,0.f};

    // 3-set rotating pipeline: set loaded at line i holds step i+2, is
    // computed at line i+2 -> cover = 2 full compute phases (> L2 latency).
    bf16x8 k1a,k2a,vla,vha, k1b,k2b,vlb,vhb, k1c,k2c,vlc,vhc;
    STEP_LOAD(0, k1a, k2a, vla, vha);
    STEP_LOAD(1, k1b, k2b, vlb, vhb);
    PIPE( 2, k1c,k2c,vlc,vhc, k1a,k2a,vla,vha)   // compute step 0
    PIPE( 3, k1a,k2a,vla,vha, k1b,k2b,vlb,vhb)   // compute step 1
    PIPE( 4, k1b,k2b,vlb,vhb, k1c,k2c,vlc,vhc)   // compute step 2
    PIPE( 5, k1c,k2c,vlc,vhc, k1a,k2a,vla,vha)   // compute step 3
    PIPE( 6, k1a,k2a,vla,vha, k1b,k2b,vlb,vhb)   // compute step 4
    PIPE( 7, k1b,k2b,vlb,vhb, k1c,k2c,vlc,vhc)   // compute step 5
    PIPE( 8, k1c,k2c,vlc,vhc, k1a,k2a,vla,vha)   // compute step 6
    PIPE( 9, k1a,k2a,vla,vha, k1b,k2b,vlb,vhb)   // compute step 7
    PIPE(10, k1b,k2b,vlb,vhb, k1c,k2c,vlc,vhc)   // compute step 8
    PIPE(11, k1c,k2c,vlc,vhc, k1a,k2a,vla,vha)   // compute step 9
    PIPE(12, k1a,k2a,vla,vha, k1b,k2b,vlb,vhb)   // compute step 10
    PIPE(13, k1b,k2b,vlb,vhb, k1c,k2c,vlc,vhc)   // compute step 11
    PIPE(14, k1c,k2c,vlc,vhc, k1a,k2a,vla,vha)   // compute step 12
    PIPE(15, k1a,k2a,vla,vha, k1b,k2b,vlb,vhb)   // compute step 13
    STEP_COMPUTE(k1c, k2c, vlc, vhc);            // step 14
    STEP_COMPUTE(k1a, k2a, vla, vha);            // step 15

    // lane holds out^T[d = quad*4+r (lo) / 16+... (hi)][n] (x sqrt(32)*3000).
    // Project 288->4 with Wp, apply deferred scale, reduce quads, and STORE
    // the per-(bh,zz) partial into this block's unique of_part region.
    const float s1 = 5.892556509887896e-05f;   // 1/(sqrt(32)*3000)
    const float* wph = Wp + h * D + quad * 4;
    float* obase = ofp + ((size_t)(bh * 8 + zz) * 4) * SQ + nw + l15;
#pragma unroll
    for (int o = 0; o < 4; ++o) {
        float cA = 0.f, cB = 0.f, cC = 0.f, cD = 0.f;
#pragma unroll
        for (int r = 0; r < 4; ++r) {
            float wlo = wph[o * 288 + r], whi = wph[o * 288 + 16 + r];
            cA += accAl[r] * wlo + accAh[r] * whi;
            cB += accBl[r] * wlo + accBh[r] * whi;
            cC += accCl[r] * wlo + accCh[r] * whi;
            cD += accDl[r] * wlo + accDh[r] * whi;
        }
        cA += __shfl_xor(cA, 16); cA += __shfl_xor(cA, 32);
        cB += __shfl_xor(cB, 16); cB += __shfl_xor(cB, 32);
        cC += __shfl_xor(cC, 16); cC += __shfl_xor(cC, 32);
        cD += __shfl_xor(cD, 16); cD += __shfl_xor(cD, 32);
        if (quad == 0) {
            float* ob = obase + (size_t)o * SQ;
            ob[0]  = cA * s1;
            ob[16] = cB * s1;
            ob[32] = cC * s1;
            ob[48] = cD * s1;
        }
    }
}

// ---------------------------------------------------------------------------
// Final: 72-way partial reduction (9 h x 8 zz) fused with 2x2-mean
// downsample + bias + residual; both tuple outputs.
// 65536 threads: 8 per output (one zz-slice each, 9-h loop), shfl reduce.
// ---------------------------------------------------------------------------
__global__ __launch_bounds__(256) void final_kernel(
    const float* __restrict__ ofp,
    const float* __restrict__ sff,
    const float* __restrict__ bp,
    float* __restrict__ dout)
{
    int t = blockIdx.x * 256 + threadIdx.x;   // 0..65535
    int out = t >> 3;                         // 0..8191 output index
    int s   = t & 7;                          // zz slice
    int i  = out & 31;
    int jj = (out >> 5) & 31;
    int bo = out >> 10;
    int o  = bo & 3;
    int b  = bo >> 2;
    int nbase = (jj * 2) * 64 + i * 2;

    float acc = 0.0f;
#pragma unroll
    for (int h = 0; h < NHEADS; ++h) {
        const float* src = ofp +
            ((size_t)(((b * NHEADS + h) * 8 + s) * 4 + o)) * SQ + nbase;
        acc += src[0] + src[1] + src[64] + src[65];
    }
    acc += __shfl_xor(acc, 1);
    acc += __shfl_xor(acc, 2);
    acc += __shfl_xor(acc, 4);
    if (s == 0) {
        float dval = 0.25f * acc + bp[o];
        dout[out]        = sff[out] + dval;
        dout[8192 + out] = dval;
    }
}

extern "C" void kernel_launch(void* const* d_in, const int* in_sizes, int n_in,
                              void* d_out, int out_size, void* d_ws, size_t ws_size,
                              hipStream_t stream)
{
    const float* second_frame = (const float*)d_in[0];
    const float* first_frame  = (const float*)d_in[1];
    const float* sff          = (const float*)d_in[2];
    const float* ffa          = (const float*)d_in[3];
    const float* Wq = (const float*)d_in[4];
    const float* bq = (const float*)d_in[5];
    const float* Wk = (const float*)d_in[6];
    const float* bk = (const float*)d_in[7];
    const float* Wv = (const float*)d_in[8];
    const float* bv = (const float*)d_in[9];
    const float* Wp = (const float*)d_in[10];
    const float* bp = (const float*)d_in[11];
    const float* Wt = (const float*)d_in[12];
    const float* bt = (const float*)d_in[13];
    float* out = (float*)d_out;

    char* ws = (char*)d_ws;
    const size_t QKV = (size_t)2 * NHEADS * SQ * D * sizeof(unsigned short);
    unsigned short* Qb = (unsigned short*)ws;
    unsigned short* Kb = (unsigned short*)(ws + QKV);
    unsigned short* Vt = (unsigned short*)(ws + 2 * QKV);
    float* tbuf = (float*)(ws + 3 * QKV);
    // of_part[18 bh][8 zz][4 o][4096 n] = 9.44 MB of partials
    float* ofp  = (float*)(ws + 3 * QKV + (size_t)2 * NHEADS * SQ * sizeof(float));

    prep_kernel<<<1152, 256, 0, stream>>>(second_frame, first_frame, ffa,
                                          Wq, bq, Wk, bk, Wv, bv, Wt, bt,
                                          Qb, Kb, Vt, tbuf);
    attn_kernel<<<16 * 18 * ZSPLIT, 256, 0, stream>>>(Qb, Kb, Vt, tbuf, Wp, ofp);
    final_kernel<<<256, 256, 0, stream>>>(ofp, sff, bp, out);
}

// Round 6
// 134.835 us; speedup vs baseline: 1.2078x; 1.0551x over previous
//
#include <hip/hip_runtime.h>
#include <hip/hip_bf16.h>
#include <cstddef>

#define NHEADS 9
#define D 32
#define SQ 4096
#define ZSPLIT 8
#define MBLK (SQ / ZSPLIT)     // 512 m per block
#define CHUNKS (MBLK / 64)     // 8 chunks of 64 m

typedef __attribute__((ext_vector_type(8))) short bf16x8;
typedef __attribute__((ext_vector_type(4))) float f32x4;

__device__ __forceinline__ unsigned int f2bf(float f) {
    unsigned int u = __float_as_uint(f);
    u += 0x7fffu + ((u >> 16) & 1u);
    return u >> 16;
}

// pack two f32 into bf16x2 by TRUNCATION: one v_perm_b32.
__device__ __forceinline__ unsigned int trunc_pk(float lo, float hi) {
    return __builtin_amdgcn_perm(__float_as_uint(hi), __float_as_uint(lo),
                                 0x07060302u);
}

// Pack 8 scores (two QK C-tiles) then relu on bf16 BIT PATTERNS:
// negative bf16 == negative i16, so relu == v_pk_max_i16(p, 0).
__device__ __forceinline__ bf16x8 relu_pack8(f32x4 s1, f32x4 s2) {
    union { unsigned int u[4]; bf16x8 v; } P;
    P.u[0] = trunc_pk(s1[0], s1[1]);
    P.u[1] = trunc_pk(s1[2], s1[3]);
    P.u[2] = trunc_pk(s2[0], s2[1]);
    P.u[3] = trunc_pk(s2[2], s2[3]);
    const bf16x8 z = {0, 0, 0, 0, 0, 0, 0, 0};
    return __builtin_elementwise_max(P.v, z);   // v_pk_max_i16 x4
}

// async global->LDS DMA, 16B per lane; LDS dest = wave-uniform base + lane*16.
__device__ __forceinline__ void gload_lds16(const unsigned short* g,
                                            unsigned short* l) {
    __builtin_amdgcn_global_load_lds(
        (const __attribute__((address_space(1))) unsigned int*)g,
        (__attribute__((address_space(3))) unsigned int*)l, 16, 0, 0);
}

// ---------------------------------------------------------------------------
// Prep: bilinear upsample (32->64, half-pixel) + 1x1 convs -> Q,K,V (bf16) + t
// One thread per (bh, n, 8-d-group).
// K: CHUNK-SLOT-PERMUTED layout [bh][chunk=n>>6][slot(n&63)][d] so attn
// K-fragments are contiguous 1KB wave-reads (pre-swizzled-global pattern).
// V: FRAGMENT-ORDERED layout — per 32-m chunk a 2KB block
//   addr = (bh*128 + m>>5)*1024 + (d>>4)*512 + ((m>>3)&3)*128 + (d&15)*8 + (m&7)
// so attn VL/VH fragments are each ONE contiguous 1KB wave-read.
// Both layouts are LINEAR in the order attn's global_load_lds lanes write,
// which is what lets attn stage via DMA with zero VGPR cost.
// ---------------------------------------------------------------------------
__global__ __launch_bounds__(256) void prep_kernel(
    const float* __restrict__ x2, const float* __restrict__ x1,
    const float* __restrict__ feat1,
    const float* __restrict__ Wq, const float* __restrict__ bq,
    const float* __restrict__ Wk, const float* __restrict__ bk,
    const float* __restrict__ Wv, const float* __restrict__ bv,
    const float* __restrict__ Wt, const float* __restrict__ bt,
    unsigned short* __restrict__ Qb, unsigned short* __restrict__ Kb,
    unsigned short* __restrict__ Vt, float* __restrict__ tbuf)
{
    __shared__ unsigned short Vls[32 * 66];   // [d][n_local], stride 66

    const int tid = threadIdx.x;
    int idx = blockIdx.x * blockDim.x + tid;   // 0 .. 2*9*4096*4-1
    int g  = idx & 3;                 // d-group: d = g*8 .. g*8+7
    int nl = tid >> 2;                // n-local 0..63 (block covers 64 n, 1 bh)
    int n  = (idx >> 2) & (SQ - 1);
    int bh = idx >> 14;               // 0..17
    int h  = bh % NHEADS;
    int b  = bh / NHEADS;

    float xs0 = x2[((size_t)b * 3 + 0) * SQ + n];
    float xs1 = x2[((size_t)b * 3 + 1) * SQ + n];
    float xs2 = x2[((size_t)b * 3 + 2) * SQ + n];
    float ys0 = x1[((size_t)b * 3 + 0) * SQ + n];
    float ys1 = x1[((size_t)b * 3 + 1) * SQ + n];
    float ys2 = x1[((size_t)b * 3 + 2) * SQ + n];

    // bilinear upsample coords: src = i*0.5 - 0.25 (half-pixel)
    int yy = n >> 6, xx = n & 63;
    int jy = yy >> 1, jx = xx >> 1;
    int j0, j1, i0, i1; float wy0, wy1, wx0, wx1;
    if (yy & 1) { j0 = jy; j1 = (jy < 31) ? jy + 1 : 31; wy0 = 0.75f; wy1 = 0.25f; }
    else        { j0 = (jy > 0) ? jy - 1 : 0; j1 = jy;   wy0 = 0.25f; wy1 = 0.75f; }
    if (xx & 1) { i0 = jx; i1 = (jx < 31) ? jx + 1 : 31; wx0 = 0.75f; wx1 = 0.25f; }
    else        { i0 = (jx > 0) ? jx - 1 : 0; i1 = jx;   wx0 = 0.25f; wx1 = 0.75f; }

    float fu[4];
#pragma unroll
    for (int c = 0; c < 4; ++c) {
        const float* f = feat1 + ((size_t)b * 4 + c) * 1024;
        fu[c] = wy0 * (wx0 * f[j0 * 32 + i0] + wx1 * f[j0 * 32 + i1]) +
                wy1 * (wx0 * f[j1 * 32 + i0] + wx1 * f[j1 * 32 + i1]);
    }

    const int d0 = g * 8;
    unsigned int qp[4], kp[4];
    float tpart = 0.0f;
#pragma unroll
    for (int j = 0; j < 8; ++j) {
        int d = d0 + j, hd = h * D + d;
        float q = bq[hd] + Wq[hd * 3] * xs0 + Wq[hd * 3 + 1] * xs1 + Wq[hd * 3 + 2] * xs2;
        float k = bk[hd] + Wk[hd * 3] * ys0 + Wk[hd * 3 + 1] * ys1 + Wk[hd * 3 + 2] * ys2;
        float v = bv[hd] + Wv[hd * 4] * fu[0] + Wv[hd * 4 + 1] * fu[1] +
                  Wv[hd * 4 + 2] * fu[2] + Wv[hd * 4 + 3] * fu[3];
        tpart += q * Wt[d];
        unsigned int qb_ = f2bf(q), kb_ = f2bf(k);
        if (j & 1) { qp[j >> 1] |= qb_ << 16; kp[j >> 1] |= kb_ << 16; }
        else       { qp[j >> 1]  = qb_;       kp[j >> 1]  = kb_; }
        Vls[d * 66 + nl] = (unsigned short)f2bf(v);   // conflict-free scatter
    }
    // reduce threshold partial over the 4-lane d-group
    tpart += __shfl_xor(tpart, 1);
    tpart += __shfl_xor(tpart, 2);
    if (g == 0) tbuf[(size_t)bh * SQ + n] = tpart + bt[0];

    *(uint4*)(Qb + ((size_t)bh * SQ + n) * D + d0) =
        make_uint4(qp[0], qp[1], qp[2], qp[3]);

    // K: permuted-slot write (bijective within each 64-row chunk)
    {
        int nl_  = n & 63;
        int slot = (nl_ & 32) + 4 * ((nl_ >> 3) & 3) + (nl_ & 3) + ((nl_ & 4) << 2);
        size_t kaddr = ((size_t)bh * SQ + (n & ~63) + slot) * D + d0;
        *(uint4*)(Kb + kaddr) = make_uint4(kp[0], kp[1], kp[2], kp[3]);
    }

    __syncthreads();
    // V write-out in fragment order: thread -> d-row r = tid>>3, n-octet
    // c4 = tid&7 (8 n each, FULL 64-n coverage, one 16B store).
    {
        int r   = tid >> 3;          // d 0..31
        int c4  = tid & 7;           // n-octet
        int blk = blockIdx.x & 63;   // 64-n range within bh
        unsigned int w0 = *(const unsigned int*)&Vls[r * 66 + c4 * 8];
        unsigned int w1 = *(const unsigned int*)&Vls[r * 66 + c4 * 8 + 2];
        unsigned int w2 = *(const unsigned int*)&Vls[r * 66 + c4 * 8 + 4];
        unsigned int w3 = *(const unsigned int*)&Vls[r * 66 + c4 * 8 + 6];
        size_t dst = ((size_t)bh * 128 + blk * 2 + (c4 >> 2)) * 1024
                   + (r >> 4) * 512 + (c4 & 3) * 128 + (r & 15) * 8;
        *(uint4*)(Vt + dst) = make_uint4(w0, w1, w2, w3);
    }
}

// ---------------------------------------------------------------------------
// Attention v6: global_load_lds staging + counted vmcnt (T3/T4).
// Round-5 post-mortem: the 3-set REGISTER pipeline was defeated by the
// compiler's VGPR allocation (stuck at 64 -> loads sunk to uses -> cover 0,
// MfmaUtil 27%). DMA staging holds in-flight state in the vmcnt counter
// instead of the register file:
//   3 LDS slots x (4KB K + 4KB V); per chunk: wait vmcnt(2) [chunk c landed,
//   c+1 in flight], raw s_barrier, issue chunk c+2 into slot (c+2)%3 (last
//   read at iter c-1, barrier-protected), compute chunk c. vmcnt NEVER
//   drains to 0 in the loop; cover = 2 compute phases (~700cy) >> L2 latency.
// K/V global layouts are fragment-linear (prep), so LDS dests are linear
// (gload_lds requirement) and every fragment read is a contiguous 1KB
// wave-read (<=2-way bank aliasing = free). Tail issues are clamped
// duplicates into dead slots to keep vmcnt arithmetic uniform.
// Epilogue: plain stores of per-(bh,zz) partials (no atomics — round 2).
// ---------------------------------------------------------------------------
#define STEP_COMPUTE(K1, K2, VL, VH)                                           \
    {                                                                          \
        f32x4 sA1 = __builtin_amdgcn_mfma_f32_16x16x32_bf16(K1, qfA, ciA, 0, 0, 0);\
        f32x4 sA2 = __builtin_amdgcn_mfma_f32_16x16x32_bf16(K2, qfA, ciA, 0, 0, 0);\
        f32x4 sB1 = __builtin_amdgcn_mfma_f32_16x16x32_bf16(K1, qfB, ciB, 0, 0, 0);\
        f32x4 sB2 = __builtin_amdgcn_mfma_f32_16x16x32_bf16(K2, qfB, ciB, 0, 0, 0);\
        f32x4 sC1 = __builtin_amdgcn_mfma_f32_16x16x32_bf16(K1, qfC, ciC, 0, 0, 0);\
        f32x4 sC2 = __builtin_amdgcn_mfma_f32_16x16x32_bf16(K2, qfC, ciC, 0, 0, 0);\
        f32x4 sD1 = __builtin_amdgcn_mfma_f32_16x16x32_bf16(K1, qfD, ciD, 0, 0, 0);\
        f32x4 sD2 = __builtin_amdgcn_mfma_f32_16x16x32_bf16(K2, qfD, ciD, 0, 0, 0);\
        bf16x8 pA = relu_pack8(sA1, sA2);                                      \
        bf16x8 pB = relu_pack8(sB1, sB2);                                      \
        bf16x8 pC = relu_pack8(sC1, sC2);                                      \
        bf16x8 pD = relu_pack8(sD1, sD2);                                      \
        accAl = __builtin_amdgcn_mfma_f32_16x16x32_bf16(VL, pA, accAl, 0, 0, 0);\
        accAh = __builtin_amdgcn_mfma_f32_16x16x32_bf16(VH, pA, accAh, 0, 0, 0);\
        accBl = __builtin_amdgcn_mfma_f32_16x16x32_bf16(VL, pB, accBl, 0, 0, 0);\
        accBh = __builtin_amdgcn_mfma_f32_16x16x32_bf16(VH, pB, accBh, 0, 0, 0);\
        accCl = __builtin_amdgcn_mfma_f32_16x16x32_bf16(VL, pC, accCl, 0, 0, 0);\
        accCh = __builtin_amdgcn_mfma_f32_16x16x32_bf16(VH, pC, accCh, 0, 0, 0);\
        accDl = __builtin_amdgcn_mfma_f32_16x16x32_bf16(VL, pD, accDl, 0, 0, 0);\
        accDh = __builtin_amdgcn_mfma_f32_16x16x32_bf16(VH, pD, accDh, 0, 0, 0);\
    }

__global__ __launch_bounds__(256, 4) void attn_kernel(
    const unsigned short* __restrict__ Qb,
    const unsigned short* __restrict__ Kb,
    const unsigned short* __restrict__ Vt,
    const float* __restrict__ tbuf,
    const float* __restrict__ Wp,
    float* __restrict__ ofp)
{
    __shared__ __align__(16) unsigned short Kls[3][2048];   // 3 x 4KB
    __shared__ __align__(16) unsigned short Vls3[3][2048];  // 3 x 4KB

    // XCD-aware bijective decode: lin -> (xcd 0..7, q 0..287) ->
    // (group-local 0..17, xblk 0..15); group = xcd*18+gl -> (bh, z).
    const int lin  = blockIdx.x;
    const int xcd  = lin & 7;
    const int q8   = lin >> 3;           // 0..287
    const int xblk = q8 & 15;
    const int gl   = q8 >> 4;            // 0..17
    const int grp  = xcd * 18 + gl;      // 0..143
    const int bh   = grp >> 3;           // 0..17
    const int zz   = grp & 7;            // 0..7
    const int h    = bh % NHEADS;
    const int n0   = xblk * 256;
    const int mc0  = zz * MBLK;
    const int tid  = threadIdx.x;
    const int wave = tid >> 6;
    const int lane = tid & 63;
    const int l15  = lane & 15;
    const int quad = lane >> 4;

    const int nw = n0 + wave * 64;

    // Q as B-fragment: B[d=quad*8+j][n=l15], 4 tiles at n offsets 0/16/32/48
    const unsigned short* qbase = Qb + ((size_t)bh * SQ + nw + l15) * D + quad * 8;
    bf16x8 qfA = *(const bf16x8*)(qbase);
    bf16x8 qfB = *(const bf16x8*)(qbase + 16 * D);
    bf16x8 qfC = *(const bf16x8*)(qbase + 32 * D);
    bf16x8 qfD = *(const bf16x8*)(qbase + 48 * D);

    const float SQRT32 = 5.656854249492381f;
    const float* tb = tbuf + (size_t)bh * SQ + nw + l15;
    float TA = tb[0]  * SQRT32;
    float TB = tb[16] * SQRT32;
    float TC = tb[32] * SQRT32;
    float TD = tb[48] * SQRT32;
    const f32x4 ciA = {-TA, -TA, -TA, -TA};
    const f32x4 ciB = {-TB, -TB, -TB, -TB};
    const f32x4 ciC = {-TC, -TC, -TC, -TC};
    const f32x4 ciD = {-TD, -TD, -TD, -TD};

    // staging sources (fragment-linear global): thread t owns 16B at t*8 hw
    const unsigned short* Kg = Kb + ((size_t)bh * SQ + mc0) * D + tid * 8;
    const unsigned short* Vg = Vt + ((size_t)bh * 128 + (mc0 >> 5)) * 1024 + tid * 8;
    const int wv = wave * 512;           // wave-uniform LDS base (halfwords)

    // fragment read offsets within a slot (halfwords)
    const int koff = l15 * 32 + quad * 8;
    const int voff = lane * 8;

#define ISSUE(C, S)                                                            \
    gload_lds16(Kg + (size_t)(C) * 2048, &Kls[S][wv]);                         \
    gload_lds16(Vg + (size_t)(C) * 2048, &Vls3[S][wv]);

#define CCHUNK(S)                                                              \
    {                                                                          \
        const unsigned short* Kp = &Kls[S][0];                                 \
        const unsigned short* Vp = &Vls3[S][0];                                \
        bf16x8 k1 = *(const bf16x8*)(Kp + koff);                               \
        bf16x8 k2 = *(const bf16x8*)(Kp + 512 + koff);                         \
        bf16x8 vl = *(const bf16x8*)(Vp + voff);                               \
        bf16x8 vh = *(const bf16x8*)(Vp + 512 + voff);                         \
        STEP_COMPUTE(k1, k2, vl, vh);                                          \
        k1 = *(const bf16x8*)(Kp + 1024 + koff);                               \
        k2 = *(const bf16x8*)(Kp + 1536 + koff);                               \
        vl = *(const bf16x8*)(Vp + 1024 + voff);                               \
        vh = *(const bf16x8*)(Vp + 1536 + voff);                               \
        STEP_COMPUTE(k1, k2, vl, vh);                                          \
    }

    f32x4 accAl = {0.f,0.f,0.f,0.f}, accAh = {0.f,0.f,0.f,0.f};
    f32x4 accBl = {0.f,0.f,0.f,0.f}, accBh = {0.f,0.f,0.f,0.f};
    f32x4 accCl = {0.f,0.f,0.f,0.f}, accCh = {0.f,0.f,0.f,0.f};
    f32x4 accDl = {0.f,0.f,0.f,0.f}, accDh = {0.f,0.f,0.f,0.f};

    // prologue: chunks 0,1 in flight (4 vm-ops)
    ISSUE(0, 0);
    ISSUE(1, 1);

#pragma unroll
    for (int c = 0; c < CHUNKS; ++c) {
        // chunk c landed; chunk c+1 stays in flight (never vmcnt 0)
        asm volatile("s_waitcnt vmcnt(2)" ::: "memory");
        __builtin_amdgcn_s_barrier();    // raw: no vmcnt drain
        {
            const int nc = (c + 2 < CHUNKS) ? c + 2 : CHUNKS - 1;  // tail: dup
            ISSUE(nc, (c + 2) % 3);      // slot last read at iter c-1
        }
        CCHUNK(c % 3);
    }
    asm volatile("s_waitcnt vmcnt(0)" ::: "memory");   // drain tail dups

    // lane holds out^T[d = quad*4+r (lo) / 16+... (hi)][n] (x sqrt(32)*3000).
    // Project 288->4 with Wp, apply deferred scale, reduce quads, and STORE
    // the per-(bh,zz) partial into this block's unique of_part region.
    const float s1 = 5.892556509887896e-05f;   // 1/(sqrt(32)*3000)
    const float* wph = Wp + h * D + quad * 4;
    float* obase = ofp + ((size_t)(bh * 8 + zz) * 4) * SQ + nw + l15;
#pragma unroll
    for (int o = 0; o < 4; ++o) {
        float cA = 0.f, cB = 0.f, cC = 0.f, cD = 0.f;
#pragma unroll
        for (int r = 0; r < 4; ++r) {
            float wlo = wph[o * 288 + r], whi = wph[o * 288 + 16 + r];
            cA += accAl[r] * wlo + accAh[r] * whi;
            cB += accBl[r] * wlo + accBh[r] * whi;
            cC += accCl[r] * wlo + accCh[r] * whi;
            cD += accDl[r] * wlo + accDh[r] * whi;
        }
        cA += __shfl_xor(cA, 16); cA += __shfl_xor(cA, 32);
        cB += __shfl_xor(cB, 16); cB += __shfl_xor(cB, 32);
        cC += __shfl_xor(cC, 16); cC += __shfl_xor(cC, 32);
        cD += __shfl_xor(cD, 16); cD += __shfl_xor(cD, 32);
        if (quad == 0) {
            float* ob = obase + (size_t)o * SQ;
            ob[0]  = cA * s1;
            ob[16] = cB * s1;
            ob[32] = cC * s1;
            ob[48] = cD * s1;
        }
    }
}

// ---------------------------------------------------------------------------
// Final: 72-way partial reduction (9 h x 8 zz) fused with 2x2-mean
// downsample + bias + residual; both tuple outputs.
// 65536 threads: 8 per output (one zz-slice each, 9-h loop), shfl reduce.
// ---------------------------------------------------------------------------
__global__ __launch_bounds__(256) void final_kernel(
    const float* __restrict__ ofp,
    const float* __restrict__ sff,
    const float* __restrict__ bp,
    float* __restrict__ dout)
{
    int t = blockIdx.x * 256 + threadIdx.x;   // 0..65535
    int out = t >> 3;                         // 0..8191 output index
    int s   = t & 7;                          // zz slice
    int i  = out & 31;
    int jj = (out >> 5) & 31;
    int bo = out >> 10;
    int o  = bo & 3;
    int b  = bo >> 2;
    int nbase = (jj * 2) * 64 + i * 2;

    float acc = 0.0f;
#pragma unroll
    for (int h = 0; h < NHEADS; ++h) {
        const float* src = ofp +
            ((size_t)(((b * NHEADS + h) * 8 + s) * 4 + o)) * SQ + nbase;
        acc += src[0] + src[1] + src[64] + src[65];
    }
    acc += __shfl_xor(acc, 1);
    acc += __shfl_xor(acc, 2);
    acc += __shfl_xor(acc, 4);
    if (s == 0) {
        float dval = 0.25f * acc + bp[o];
        dout[out]        = sff[out] + dval;
        dout[8192 + out] = dval;
    }
}

extern "C" void kernel_launch(void* const* d_in, const int* in_sizes, int n_in,
                              void* d_out, int out_size, void* d_ws, size_t ws_size,
                              hipStream_t stream)
{
    const float* second_frame = (const float*)d_in[0];
    const float* first_frame  = (const float*)d_in[1];
    const float* sff          = (const float*)d_in[2];
    const float* ffa          = (const float*)d_in[3];
    const float* Wq = (const float*)d_in[4];
    const float* bq = (const float*)d_in[5];
    const float* Wk = (const float*)d_in[6];
    const float* bk = (const float*)d_in[7];
    const float* Wv = (const float*)d_in[8];
    const float* bv = (const float*)d_in[9];
    const float* Wp = (const float*)d_in[10];
    const float* bp = (const float*)d_in[11];
    const float* Wt = (const float*)d_in[12];
    const float* bt = (const float*)d_in[13];
    float* out = (float*)d_out;

    char* ws = (char*)d_ws;
    const size_t QKV = (size_t)2 * NHEADS * SQ * D * sizeof(unsigned short);
    unsigned short* Qb = (unsigned short*)ws;
    unsigned short* Kb = (unsigned short*)(ws + QKV);
    unsigned short* Vt = (unsigned short*)(ws + 2 * QKV);
    float* tbuf = (float*)(ws + 3 * QKV);
    // of_part[18 bh][8 zz][4 o][4096 n] = 9.44 MB of partials
    float* ofp  = (float*)(ws + 3 * QKV + (size_t)2 * NHEADS * SQ * sizeof(float));

    prep_kernel<<<1152, 256, 0, stream>>>(second_frame, first_frame, ffa,
                                          Wq, bq, Wk, bk, Wv, bv, Wt, bt,
                                          Qb, Kb, Vt, tbuf);
    attn_kernel<<<16 * 18 * ZSPLIT, 256, 0, stream>>>(Qb, Kb, Vt, tbuf, Wp, ofp);
    final_kernel<<<256, 256, 0, stream>>>(ofp, sff, bp, out);
}

// Round 7
// 134.759 us; speedup vs baseline: 1.2085x; 1.0006x over previous
//
#include <hip/hip_runtime.h>
#include <hip/hip_bf16.h>
#include <cstddef>

#define NHEADS 9
#define D 32
#define SQ 4096
#define ZSPLIT 8
#define MBLK (SQ / ZSPLIT)     // 512 m per block
#define CHUNKS (MBLK / 64)     // 8 chunks of 64 m

typedef __attribute__((ext_vector_type(8))) short bf16x8;
typedef __attribute__((ext_vector_type(4))) float f32x4;

__device__ __forceinline__ unsigned int f2bf(float f) {
    unsigned int u = __float_as_uint(f);
    u += 0x7fffu + ((u >> 16) & 1u);
    return u >> 16;
}

// pack two f32 into bf16x2 by TRUNCATION: one v_perm_b32.
__device__ __forceinline__ unsigned int trunc_pk(float lo, float hi) {
    return __builtin_amdgcn_perm(__float_as_uint(hi), __float_as_uint(lo),
                                 0x07060302u);
}

// Pack 8 scores (two QK C-tiles) then relu on bf16 BIT PATTERNS:
// negative bf16 == negative i16, so relu == v_pk_max_i16(p, 0).
__device__ __forceinline__ bf16x8 relu_pack8(f32x4 s1, f32x4 s2) {
    union { unsigned int u[4]; bf16x8 v; } P;
    P.u[0] = trunc_pk(s1[0], s1[1]);
    P.u[1] = trunc_pk(s1[2], s1[3]);
    P.u[2] = trunc_pk(s2[0], s2[1]);
    P.u[3] = trunc_pk(s2[2], s2[3]);
    const bf16x8 z = {0, 0, 0, 0, 0, 0, 0, 0};
    return __builtin_elementwise_max(P.v, z);   // v_pk_max_i16 x4
}

// async global->LDS DMA, 16B per lane; LDS dest = wave-uniform base + lane*16.
__device__ __forceinline__ void gload_lds16(const unsigned short* g,
                                            unsigned short* l) {
    __builtin_amdgcn_global_load_lds(
        (const __attribute__((address_space(1))) unsigned int*)g,
        (__attribute__((address_space(3))) unsigned int*)l, 16, 0, 0);
}

// ---------------------------------------------------------------------------
// Prep: bilinear upsample (32->64, half-pixel) + 1x1 convs -> Q,K,V (bf16) + t
// One thread per (bh, n, 8-d-group).
// K: CHUNK-SLOT-PERMUTED layout [bh][chunk=n>>6][slot(n&63)][d] so attn
// K-fragments are contiguous 1KB wave-reads (pre-swizzled-global pattern).
// V: FRAGMENT-ORDERED layout — per 32-m chunk a 2KB block
//   addr = (bh*128 + m>>5)*1024 + (d>>4)*512 + ((m>>3)&3)*128 + (d&15)*8 + (m&7)
// so attn VL/VH fragments are each ONE contiguous 1KB wave-read.
// Both layouts are LINEAR in the order attn's global_load_lds lanes write,
// which is what lets attn stage via DMA with zero VGPR cost.
// ---------------------------------------------------------------------------
__global__ __launch_bounds__(256) void prep_kernel(
    const float* __restrict__ x2, const float* __restrict__ x1,
    const float* __restrict__ feat1,
    const float* __restrict__ Wq, const float* __restrict__ bq,
    const float* __restrict__ Wk, const float* __restrict__ bk,
    const float* __restrict__ Wv, const float* __restrict__ bv,
    const float* __restrict__ Wt, const float* __restrict__ bt,
    unsigned short* __restrict__ Qb, unsigned short* __restrict__ Kb,
    unsigned short* __restrict__ Vt, float* __restrict__ tbuf)
{
    __shared__ unsigned short Vls[32 * 66];   // [d][n_local], stride 66

    const int tid = threadIdx.x;
    int idx = blockIdx.x * blockDim.x + tid;   // 0 .. 2*9*4096*4-1
    int g  = idx & 3;                 // d-group: d = g*8 .. g*8+7
    int nl = tid >> 2;                // n-local 0..63 (block covers 64 n, 1 bh)
    int n  = (idx >> 2) & (SQ - 1);
    int bh = idx >> 14;               // 0..17
    int h  = bh % NHEADS;
    int b  = bh / NHEADS;

    float xs0 = x2[((size_t)b * 3 + 0) * SQ + n];
    float xs1 = x2[((size_t)b * 3 + 1) * SQ + n];
    float xs2 = x2[((size_t)b * 3 + 2) * SQ + n];
    float ys0 = x1[((size_t)b * 3 + 0) * SQ + n];
    float ys1 = x1[((size_t)b * 3 + 1) * SQ + n];
    float ys2 = x1[((size_t)b * 3 + 2) * SQ + n];

    // bilinear upsample coords: src = i*0.5 - 0.25 (half-pixel)
    int yy = n >> 6, xx = n & 63;
    int jy = yy >> 1, jx = xx >> 1;
    int j0, j1, i0, i1; float wy0, wy1, wx0, wx1;
    if (yy & 1) { j0 = jy; j1 = (jy < 31) ? jy + 1 : 31; wy0 = 0.75f; wy1 = 0.25f; }
    else        { j0 = (jy > 0) ? jy - 1 : 0; j1 = jy;   wy0 = 0.25f; wy1 = 0.75f; }
    if (xx & 1) { i0 = jx; i1 = (jx < 31) ? jx + 1 : 31; wx0 = 0.75f; wx1 = 0.25f; }
    else        { i0 = (jx > 0) ? jx - 1 : 0; i1 = jx;   wx0 = 0.25f; wx1 = 0.75f; }

    float fu[4];
#pragma unroll
    for (int c = 0; c < 4; ++c) {
        const float* f = feat1 + ((size_t)b * 4 + c) * 1024;
        fu[c] = wy0 * (wx0 * f[j0 * 32 + i0] + wx1 * f[j0 * 32 + i1]) +
                wy1 * (wx0 * f[j1 * 32 + i0] + wx1 * f[j1 * 32 + i1]);
    }

    const int d0 = g * 8;
    unsigned int qp[4], kp[4];
    float tpart = 0.0f;
#pragma unroll
    for (int j = 0; j < 8; ++j) {
        int d = d0 + j, hd = h * D + d;
        float q = bq[hd] + Wq[hd * 3] * xs0 + Wq[hd * 3 + 1] * xs1 + Wq[hd * 3 + 2] * xs2;
        float k = bk[hd] + Wk[hd * 3] * ys0 + Wk[hd * 3 + 1] * ys1 + Wk[hd * 3 + 2] * ys2;
        float v = bv[hd] + Wv[hd * 4] * fu[0] + Wv[hd * 4 + 1] * fu[1] +
                  Wv[hd * 4 + 2] * fu[2] + Wv[hd * 4 + 3] * fu[3];
        tpart += q * Wt[d];
        unsigned int qb_ = f2bf(q), kb_ = f2bf(k);
        if (j & 1) { qp[j >> 1] |= qb_ << 16; kp[j >> 1] |= kb_ << 16; }
        else       { qp[j >> 1]  = qb_;       kp[j >> 1]  = kb_; }
        Vls[d * 66 + nl] = (unsigned short)f2bf(v);   // conflict-free scatter
    }
    // reduce threshold partial over the 4-lane d-group
    tpart += __shfl_xor(tpart, 1);
    tpart += __shfl_xor(tpart, 2);
    if (g == 0) tbuf[(size_t)bh * SQ + n] = tpart + bt[0];

    *(uint4*)(Qb + ((size_t)bh * SQ + n) * D + d0) =
        make_uint4(qp[0], qp[1], qp[2], qp[3]);

    // K: permuted-slot write (bijective within each 64-row chunk)
    {
        int nl_  = n & 63;
        int slot = (nl_ & 32) + 4 * ((nl_ >> 3) & 3) + (nl_ & 3) + ((nl_ & 4) << 2);
        size_t kaddr = ((size_t)bh * SQ + (n & ~63) + slot) * D + d0;
        *(uint4*)(Kb + kaddr) = make_uint4(kp[0], kp[1], kp[2], kp[3]);
    }

    __syncthreads();
    // V write-out in fragment order: thread -> d-row r = tid>>3, n-octet
    // c4 = tid&7 (8 n each, FULL 64-n coverage, one 16B store).
    {
        int r   = tid >> 3;          // d 0..31
        int c4  = tid & 7;           // n-octet
        int blk = blockIdx.x & 63;   // 64-n range within bh
        unsigned int w0 = *(const unsigned int*)&Vls[r * 66 + c4 * 8];
        unsigned int w1 = *(const unsigned int*)&Vls[r * 66 + c4 * 8 + 2];
        unsigned int w2 = *(const unsigned int*)&Vls[r * 66 + c4 * 8 + 4];
        unsigned int w3 = *(const unsigned int*)&Vls[r * 66 + c4 * 8 + 6];
        size_t dst = ((size_t)bh * 128 + blk * 2 + (c4 >> 2)) * 1024
                   + (r >> 4) * 512 + (c4 & 3) * 128 + (r & 15) * 8;
        *(uint4*)(Vt + dst) = make_uint4(w0, w1, w2, w3);
    }
}

// ---------------------------------------------------------------------------
// Attention v7: 8-WAVE blocks (512 threads, 512 n) sharing one DMA staging.
// Round-6 structure (global_load_lds + counted vmcnt, 3 LDS slots) retained;
// changes: (1) block covers 512 n -> each K/V chunk staged 8x total instead
// of 16x, and each wave issues exactly ONE gload_lds per chunk (waves 0-3
// stage K quarters, waves 4-7 V quarters). Per-wave VGPR state UNCHANGED
// (round-5 lesson: keep register pressure flat). (2) T5 s_setprio(1) around
// the MFMA+pack cluster — waves now have genuine role diversity (DMA-issue
// vs compute), the regime where setprio measured +4..25%.
// Ordering: each wave waits vmcnt(1) for ITS OWN chunk-c quarter, then the
// barrier publishes all quarters; compute c reads K+V staged by all waves.
// Slot (c+2)%3 is re-written only after the iter-c barrier proves everyone
// finished reading it at iter c-1. vmcnt never drains to 0 in the loop.
// Epilogue: plain stores of per-(bh,zz) partials (no atomics — round 2).
// ---------------------------------------------------------------------------
#define STEP_COMPUTE(K1, K2, VL, VH)                                           \
    {                                                                          \
        f32x4 sA1 = __builtin_amdgcn_mfma_f32_16x16x32_bf16(K1, qfA, ciA, 0, 0, 0);\
        f32x4 sA2 = __builtin_amdgcn_mfma_f32_16x16x32_bf16(K2, qfA, ciA, 0, 0, 0);\
        f32x4 sB1 = __builtin_amdgcn_mfma_f32_16x16x32_bf16(K1, qfB, ciB, 0, 0, 0);\
        f32x4 sB2 = __builtin_amdgcn_mfma_f32_16x16x32_bf16(K2, qfB, ciB, 0, 0, 0);\
        f32x4 sC1 = __builtin_amdgcn_mfma_f32_16x16x32_bf16(K1, qfC, ciC, 0, 0, 0);\
        f32x4 sC2 = __builtin_amdgcn_mfma_f32_16x16x32_bf16(K2, qfC, ciC, 0, 0, 0);\
        f32x4 sD1 = __builtin_amdgcn_mfma_f32_16x16x32_bf16(K1, qfD, ciD, 0, 0, 0);\
        f32x4 sD2 = __builtin_amdgcn_mfma_f32_16x16x32_bf16(K2, qfD, ciD, 0, 0, 0);\
        bf16x8 pA = relu_pack8(sA1, sA2);                                      \
        bf16x8 pB = relu_pack8(sB1, sB2);                                      \
        bf16x8 pC = relu_pack8(sC1, sC2);                                      \
        bf16x8 pD = relu_pack8(sD1, sD2);                                      \
        accAl = __builtin_amdgcn_mfma_f32_16x16x32_bf16(VL, pA, accAl, 0, 0, 0);\
        accAh = __builtin_amdgcn_mfma_f32_16x16x32_bf16(VH, pA, accAh, 0, 0, 0);\
        accBl = __builtin_amdgcn_mfma_f32_16x16x32_bf16(VL, pB, accBl, 0, 0, 0);\
        accBh = __builtin_amdgcn_mfma_f32_16x16x32_bf16(VH, pB, accBh, 0, 0, 0);\
        accCl = __builtin_amdgcn_mfma_f32_16x16x32_bf16(VL, pC, accCl, 0, 0, 0);\
        accCh = __builtin_amdgcn_mfma_f32_16x16x32_bf16(VH, pC, accCh, 0, 0, 0);\
        accDl = __builtin_amdgcn_mfma_f32_16x16x32_bf16(VL, pD, accDl, 0, 0, 0);\
        accDh = __builtin_amdgcn_mfma_f32_16x16x32_bf16(VH, pD, accDh, 0, 0, 0);\
    }

__global__ __launch_bounds__(512, 4) void attn_kernel(
    const unsigned short* __restrict__ Qb,
    const unsigned short* __restrict__ Kb,
    const unsigned short* __restrict__ Vt,
    const float* __restrict__ tbuf,
    const float* __restrict__ Wp,
    float* __restrict__ ofp)
{
    __shared__ __align__(16) unsigned short Kls[3][2048];   // 3 x 4KB
    __shared__ __align__(16) unsigned short Vls3[3][2048];  // 3 x 4KB

    // XCD-aware bijective decode: lin -> (xcd 0..7, q 0..143) ->
    // (group-local 0..17, xblk 0..7); group = xcd*18+gl -> (bh, z).
    const int lin  = blockIdx.x;
    const int xcd  = lin & 7;
    const int q8   = lin >> 3;           // 0..143
    const int xblk = q8 & 7;
    const int gl   = q8 >> 3;            // 0..17
    const int grp  = xcd * 18 + gl;      // 0..143
    const int bh   = grp >> 3;           // 0..17
    const int zz   = grp & 7;            // 0..7
    const int h    = bh % NHEADS;
    const int n0   = xblk * 512;
    const int mc0  = zz * MBLK;
    const int tid  = threadIdx.x;
    const int wave = tid >> 6;           // 0..7
    const int lane = tid & 63;
    const int l15  = lane & 15;
    const int quad = lane >> 4;

    const int nw = n0 + wave * 64;

    // Q as B-fragment: B[d=quad*8+j][n=l15], 4 tiles at n offsets 0/16/32/48
    const unsigned short* qbase = Qb + ((size_t)bh * SQ + nw + l15) * D + quad * 8;
    bf16x8 qfA = *(const bf16x8*)(qbase);
    bf16x8 qfB = *(const bf16x8*)(qbase + 16 * D);
    bf16x8 qfC = *(const bf16x8*)(qbase + 32 * D);
    bf16x8 qfD = *(const bf16x8*)(qbase + 48 * D);

    const float SQRT32 = 5.656854249492381f;
    const float* tb = tbuf + (size_t)bh * SQ + nw + l15;
    float TA = tb[0]  * SQRT32;
    float TB = tb[16] * SQRT32;
    float TC = tb[32] * SQRT32;
    float TD = tb[48] * SQRT32;
    const f32x4 ciA = {-TA, -TA, -TA, -TA};
    const f32x4 ciB = {-TB, -TB, -TB, -TB};
    const f32x4 ciC = {-TC, -TC, -TC, -TC};
    const f32x4 ciD = {-TD, -TD, -TD, -TD};

    // staging: waves 0-3 stage K quarters, waves 4-7 stage V quarters.
    // src per lane = chunk base + quarter*512 + lane*8 hw (fragment-linear);
    // dest = wave-uniform slot base + quarter*512 (HW adds lane*16B).
    const int qtr = wave & 3;
    const unsigned short* Sg =
        (wave < 4) ? (Kb + ((size_t)bh * SQ + mc0) * D + qtr * 512 + lane * 8)
                   : (Vt + ((size_t)bh * 128 + (mc0 >> 5)) * 1024 + qtr * 512 + lane * 8);
    const int sdoff = qtr * 512;

    // fragment read offsets within a slot (halfwords)
    const int koff = l15 * 32 + quad * 8;
    const int voff = lane * 8;

#define ISSUE(C, S)                                                            \
    gload_lds16(Sg + (size_t)(C) * 2048,                                       \
                ((wave < 4) ? &Kls[S][sdoff] : &Vls3[S][sdoff]));

#define CCHUNK(S)                                                              \
    {                                                                          \
        const unsigned short* Kp = &Kls[S][0];                                 \
        const unsigned short* Vp = &Vls3[S][0];                                \
        bf16x8 k1 = *(const bf16x8*)(Kp + koff);                               \
        bf16x8 k2 = *(const bf16x8*)(Kp + 512 + koff);                         \
        bf16x8 vl = *(const bf16x8*)(Vp + voff);                               \
        bf16x8 vh = *(const bf16x8*)(Vp + 512 + voff);                         \
        __builtin_amdgcn_s_setprio(1);                                         \
        STEP_COMPUTE(k1, k2, vl, vh);                                          \
        __builtin_amdgcn_s_setprio(0);                                         \
        k1 = *(const bf16x8*)(Kp + 1024 + koff);                               \
        k2 = *(const bf16x8*)(Kp + 1536 + koff);                               \
        vl = *(const bf16x8*)(Vp + 1024 + voff);                               \
        vh = *(const bf16x8*)(Vp + 1536 + voff);                               \
        __builtin_amdgcn_s_setprio(1);                                         \
        STEP_COMPUTE(k1, k2, vl, vh);                                          \
        __builtin_amdgcn_s_setprio(0);                                         \
    }

    f32x4 accAl = {0.f,0.f,0.f,0.f}, accAh = {0.f,0.f,0.f,0.f};
    f32x4 accBl = {0.f,0.f,0.f,0.f}, accBh = {0.f,0.f,0.f,0.f};
    f32x4 accCl = {0.f,0.f,0.f,0.f}, accCh = {0.f,0.f,0.f,0.f};
    f32x4 accDl = {0.f,0.f,0.f,0.f}, accDh = {0.f,0.f,0.f,0.f};

    // prologue: chunks 0,1 in flight (1 vm-op per wave per chunk)
    ISSUE(0, 0);
    ISSUE(1, 1);

#pragma unroll
    for (int c = 0; c < CHUNKS; ++c) {
        // own chunk-c quarter landed; chunk c+1 stays in flight (never 0)
        asm volatile("s_waitcnt vmcnt(1)" ::: "memory");
        __builtin_amdgcn_s_barrier();    // publishes all waves' quarters
        {
            const int nc = (c + 2 < CHUNKS) ? c + 2 : CHUNKS - 1;  // tail: dup
            ISSUE(nc, (c + 2) % 3);      // slot last read at iter c-1
        }
        CCHUNK(c % 3);
    }
    asm volatile("s_waitcnt vmcnt(0)" ::: "memory");   // drain tail dups

    // lane holds out^T[d = quad*4+r (lo) / 16+... (hi)][n] (x sqrt(32)*3000).
    // Project 288->4 with Wp, apply deferred scale, reduce quads, and STORE
    // the per-(bh,zz) partial into this block's unique of_part region.
    const float s1 = 5.892556509887896e-05f;   // 1/(sqrt(32)*3000)
    const float* wph = Wp + h * D + quad * 4;
    float* obase = ofp + ((size_t)(bh * 8 + zz) * 4) * SQ + nw + l15;
#pragma unroll
    for (int o = 0; o < 4; ++o) {
        float cA = 0.f, cB = 0.f, cC = 0.f, cD = 0.f;
#pragma unroll
        for (int r = 0; r < 4; ++r) {
            float wlo = wph[o * 288 + r], whi = wph[o * 288 + 16 + r];
            cA += accAl[r] * wlo + accAh[r] * whi;
            cB += accBl[r] * wlo + accBh[r] * whi;
            cC += accCl[r] * wlo + accCh[r] * whi;
            cD += accDl[r] * wlo + accDh[r] * whi;
        }
        cA += __shfl_xor(cA, 16); cA += __shfl_xor(cA, 32);
        cB += __shfl_xor(cB, 16); cB += __shfl_xor(cB, 32);
        cC += __shfl_xor(cC, 16); cC += __shfl_xor(cC, 32);
        cD += __shfl_xor(cD, 16); cD += __shfl_xor(cD, 32);
        if (quad == 0) {
            float* ob = obase + (size_t)o * SQ;
            ob[0]  = cA * s1;
            ob[16] = cB * s1;
            ob[32] = cC * s1;
            ob[48] = cD * s1;
        }
    }
}

// ---------------------------------------------------------------------------
// Final: 72-way partial reduction (9 h x 8 zz) fused with 2x2-mean
// downsample + bias + residual; both tuple outputs.
// 65536 threads: 8 per output (one zz-slice each, 9-h loop), shfl reduce.
// ---------------------------------------------------------------------------
__global__ __launch_bounds__(256) void final_kernel(
    const float* __restrict__ ofp,
    const float* __restrict__ sff,
    const float* __restrict__ bp,
    float* __restrict__ dout)
{
    int t = blockIdx.x * 256 + threadIdx.x;   // 0..65535
    int out = t >> 3;                         // 0..8191 output index
    int s   = t & 7;                          // zz slice
    int i  = out & 31;
    int jj = (out >> 5) & 31;
    int bo = out >> 10;
    int o  = bo & 3;
    int b  = bo >> 2;
    int nbase = (jj * 2) * 64 + i * 2;

    float acc = 0.0f;
#pragma unroll
    for (int h = 0; h < NHEADS; ++h) {
        const float* src = ofp +
            ((size_t)(((b * NHEADS + h) * 8 + s) * 4 + o)) * SQ + nbase;
        acc += src[0] + src[1] + src[64] + src[65];
    }
    acc += __shfl_xor(acc, 1);
    acc += __shfl_xor(acc, 2);
    acc += __shfl_xor(acc, 4);
    if (s == 0) {
        float dval = 0.25f * acc + bp[o];
        dout[out]        = sff[out] + dval;
        dout[8192 + out] = dval;
    }
}

extern "C" void kernel_launch(void* const* d_in, const int* in_sizes, int n_in,
                              void* d_out, int out_size, void* d_ws, size_t ws_size,
                              hipStream_t stream)
{
    const float* second_frame = (const float*)d_in[0];
    const float* first_frame  = (const float*)d_in[1];
    const float* sff          = (const float*)d_in[2];
    const float* ffa          = (const float*)d_in[3];
    const float* Wq = (const float*)d_in[4];
    const float* bq = (const float*)d_in[5];
    const float* Wk = (const float*)d_in[6];
    const float* bk = (const float*)d_in[7];
    const float* Wv = (const float*)d_in[8];
    const float* bv = (const float*)d_in[9];
    const float* Wp = (const float*)d_in[10];
    const float* bp = (const float*)d_in[11];
    const float* Wt = (const float*)d_in[12];
    const float* bt = (const float*)d_in[13];
    float* out = (float*)d_out;

    char* ws = (char*)d_ws;
    const size_t QKV = (size_t)2 * NHEADS * SQ * D * sizeof(unsigned short);
    unsigned short* Qb = (unsigned short*)ws;
    unsigned short* Kb = (unsigned short*)(ws + QKV);
    unsigned short* Vt = (unsigned short*)(ws + 2 * QKV);
    float* tbuf = (float*)(ws + 3 * QKV);
    // of_part[18 bh][8 zz][4 o][4096 n] = 9.44 MB of partials
    float* ofp  = (float*)(ws + 3 * QKV + (size_t)2 * NHEADS * SQ * sizeof(float));

    prep_kernel<<<1152, 256, 0, stream>>>(second_frame, first_frame, ffa,
                                          Wq, bq, Wk, bk, Wv, bv, Wt, bt,
                                          Qb, Kb, Vt, tbuf);
    attn_kernel<<<8 * 18 * ZSPLIT, 512, 0, stream>>>(Qb, Kb, Vt, tbuf, Wp, ofp);
    final_kernel<<<256, 256, 0, stream>>>(ofp, sff, bp, out);
}